// Round 1
// baseline (970.089 us; speedup 1.0000x reference)
//
#include <hip/hip_runtime.h>
#include <math.h>

#define N_NODES 100000
#define N_EDGES 1600000

__global__ __launch_bounds__(256) void k_init_deg(float* __restrict__ deg) {
    int i = blockIdx.x * 256 + threadIdx.x;
    if (i < N_NODES) deg[i] = 1.0f;
}

__global__ __launch_bounds__(256) void k_count_deg(const int* __restrict__ dst,
                                                   float* __restrict__ deg) {
    int e = blockIdx.x * 256 + threadIdx.x;
    if (e < N_EDGES) atomicAdd(&deg[dst[e]], 1.0f);
}

__global__ __launch_bounds__(256) void k_dinv(const float* __restrict__ deg,
                                              float* __restrict__ dinv) {
    int i = blockIdx.x * 256 + threadIdx.x;
    if (i < N_NODES) dinv[i] = rsqrtf(deg[i]);
}

// C[N x OUT] = A[N x K] @ W[K x OUT] (+bias, +tanh optional)
// 256 threads, BR=32 rows per block. W and A-tile staged in LDS.
template<int K, int OUT, bool BIAS, bool TANH>
__global__ __launch_bounds__(256) void k_gemm(const float* __restrict__ A,
                                              const float* __restrict__ W,
                                              const float* __restrict__ bias,
                                              float* __restrict__ C) {
    constexpr int BR = 32;
    __shared__ float Wld[K * OUT];
    __shared__ float Ald[BR * K];
    const int tid = threadIdx.x;
    for (int i = tid; i < K * OUT; i += 256) Wld[i] = W[i];
    const long row0 = (long)blockIdx.x * BR;
    const float4* A4 = reinterpret_cast<const float4*>(A + row0 * K);
    float4* Ald4 = reinterpret_cast<float4*>(Ald);
    constexpr int NV = BR * K / 4;
    for (int i = tid; i < NV; i += 256) Ald4[i] = A4[i];
    __syncthreads();

    constexpr int RG = 256 / OUT;   // row groups covered per k-iteration
    constexpr int RPT = BR / RG;    // rows per thread
    const int col = tid % OUT;
    const int rg = tid / OUT;
    float acc[RPT];
#pragma unroll
    for (int j = 0; j < RPT; ++j) acc[j] = 0.f;
    for (int k = 0; k < K; ++k) {
        float w = Wld[k * OUT + col];
#pragma unroll
        for (int j = 0; j < RPT; ++j)
            acc[j] += Ald[(rg + j * RG) * K + k] * w;
    }
#pragma unroll
    for (int j = 0; j < RPT; ++j) {
        float v = acc[j];
        if (BIAS) v += bias[col];
        if (TANH) v = tanhf(v);
        C[(row0 + rg + j * RG) * OUT + col] = v;
    }
}

// agg[i] = xl[i] * (1/deg[node]) + bias[col]   (self-loop term + bias)
__global__ __launch_bounds__(256) void k_init_agg(const float* __restrict__ xl,
                                                  const float* __restrict__ dinv,
                                                  const float* __restrict__ bias,
                                                  float* __restrict__ agg) {
    int i = blockIdx.x * 256 + threadIdx.x;  // over N*64
    int node = i >> 6;
    int col = i & 63;
    float di = dinv[node];
    agg[i] = xl[i] * (di * di) + bias[col];
}

// one edge per 64-lane wave; lane = feature
__global__ __launch_bounds__(256) void k_scatter(const int* __restrict__ src,
                                                 const int* __restrict__ dst,
                                                 const float* __restrict__ dinv,
                                                 const float* __restrict__ xl,
                                                 float* __restrict__ agg) {
    const int e = blockIdx.x * 4 + (threadIdx.x >> 6);
    const int lane = threadIdx.x & 63;
    const int s = src[e];
    const int d = dst[e];
    const float nrm = dinv[s] * dinv[d];
    atomicAdd(&agg[(long)d * 64 + lane], xl[(long)s * 64 + lane] * nrm);
}

__global__ __launch_bounds__(256) void k_tanh_ip(float* __restrict__ h) {
    int i = blockIdx.x * 256 + threadIdx.x;
    h[i] = tanhf(h[i]);
}

// out[n] = sum_k h[n*32+k] * W[k] + b   (final 32 -> 1)
__global__ __launch_bounds__(256) void k_fc2(const float* __restrict__ h,
                                             const float* __restrict__ W,
                                             const float* __restrict__ b,
                                             float* __restrict__ out) {
    int i = blockIdx.x * 256 + threadIdx.x;
    if (i >= N_NODES) return;
    float acc = b[0];
#pragma unroll
    for (int k = 0; k < 32; ++k) acc += h[(long)i * 32 + k] * W[k];
    out[i] = acc;
}

extern "C" void kernel_launch(void* const* d_in, const int* in_sizes, int n_in,
                              void* d_out, int out_size, void* d_ws, size_t ws_size,
                              hipStream_t stream) {
    const float* x    = (const float*)d_in[0];
    const int*   eidx = (const int*)d_in[1];
    const float* cW0  = (const float*)d_in[2];
    const float* cb0  = (const float*)d_in[3];
    const float* cW1  = (const float*)d_in[4];
    const float* cb1  = (const float*)d_in[5];
    const float* fW0  = (const float*)d_in[6];
    const float* fb0  = (const float*)d_in[7];
    const float* fW1  = (const float*)d_in[8];
    const float* fb1  = (const float*)d_in[9];
    const float* fW2  = (const float*)d_in[10];
    const float* fb2  = (const float*)d_in[11];
    float* out = (float*)d_out;

    const int* src = eidx;
    const int* dst = eidx + N_EDGES;

    float* deg  = (float*)d_ws;
    float* dinv = deg + N_NODES;
    float* bufA = dinv + N_NODES;                 // N x 64
    float* bufB = bufA + (size_t)N_NODES * 64;    // N x 64

    const int nThreads = 256;
    const int gN   = (N_NODES + 255) / 256;       // 391
    const int gE   = N_EDGES / 256;               // 6250
    const int gNF  = N_NODES * 64 / 256;          // 25000
    const int gRow = N_NODES / 32;                // 3125
    const int gEw  = N_EDGES / 4;                 // 400000

    // degrees
    k_init_deg<<<gN, nThreads, 0, stream>>>(deg);
    k_count_deg<<<gE, nThreads, 0, stream>>>(dst, deg);
    k_dinv<<<gN, nThreads, 0, stream>>>(deg, dinv);

    // conv layer 0: xl0 = x @ cW0 -> bufA
    k_gemm<128, 64, false, false><<<gRow, nThreads, 0, stream>>>(x, cW0, nullptr, bufA);
    k_init_agg<<<gNF, nThreads, 0, stream>>>(bufA, dinv, cb0, bufB);
    k_scatter<<<gEw, nThreads, 0, stream>>>(src, dst, dinv, bufA, bufB);
    k_tanh_ip<<<gNF, nThreads, 0, stream>>>(bufB);      // bufB = h1

    // conv layer 1: xl1 = h1 @ cW1 -> bufA
    k_gemm<64, 64, false, false><<<gRow, nThreads, 0, stream>>>(bufB, cW1, nullptr, bufA);
    k_init_agg<<<gNF, nThreads, 0, stream>>>(bufA, dinv, cb1, bufB);
    k_scatter<<<gEw, nThreads, 0, stream>>>(src, dst, dinv, bufA, bufB);
    k_tanh_ip<<<gNF, nThreads, 0, stream>>>(bufB);      // bufB = h2

    // fc0: tanh(h2 @ fW0 + fb0) -> bufA
    k_gemm<64, 64, true, true><<<gRow, nThreads, 0, stream>>>(bufB, fW0, fb0, bufA);
    // fc1: tanh(bufA @ fW1 + fb1) -> bufB (N x 32)
    k_gemm<64, 32, true, true><<<gRow, nThreads, 0, stream>>>(bufA, fW1, fb1, bufB);
    // fc2: bufB @ fW2 + fb2 -> out
    k_fc2<<<gN, nThreads, 0, stream>>>(bufB, fW2, fb2, out);
}

// Round 2
// 661.791 us; speedup vs baseline: 1.4659x; 1.4659x over previous
//
#include <hip/hip_runtime.h>
#include <math.h>

#define N_NODES 100000
#define N_EDGES 1600000
#define NBLK_N 391   // ceil(N/256)

// ---------------- CSR build ----------------

__global__ __launch_bounds__(256) void k_zero_u32(unsigned* __restrict__ p, int n) {
    int i = blockIdx.x * 256 + threadIdx.x;
    if (i < n) p[i] = 0u;
}

__global__ __launch_bounds__(256) void k_hist(const int* __restrict__ dst,
                                              unsigned* __restrict__ hist) {
    int e = blockIdx.x * 256 + threadIdx.x;
    if (e < N_EDGES) atomicAdd(&hist[dst[e]], 1u);
}

__global__ __launch_bounds__(256) void k_dinv(const unsigned* __restrict__ hist,
                                              float* __restrict__ dinv) {
    int i = blockIdx.x * 256 + threadIdx.x;
    if (i < N_NODES) dinv[i] = rsqrtf((float)(hist[i] + 1u));
}

__global__ __launch_bounds__(256) void k_blocksum(const unsigned* __restrict__ hist,
                                                  unsigned* __restrict__ bs) {
    __shared__ unsigned s[256];
    int i = blockIdx.x * 256 + threadIdx.x;
    unsigned v = (i < N_NODES) ? hist[i] : 0u;
    s[threadIdx.x] = v;
    __syncthreads();
    for (int o = 128; o > 0; o >>= 1) {
        if (threadIdx.x < o) s[threadIdx.x] += s[threadIdx.x + o];
        __syncthreads();
    }
    if (threadIdx.x == 0) bs[blockIdx.x] = s[0];
}

// single block: exclusive scan of bs[NBLK_N] (NBLK_N <= 512)
__global__ __launch_bounds__(512) void k_scanbs(unsigned* __restrict__ bs) {
    __shared__ unsigned s[512];
    int tid = threadIdx.x;
    unsigned v = (tid < NBLK_N) ? bs[tid] : 0u;
    s[tid] = v;
    __syncthreads();
    for (int o = 1; o < 512; o <<= 1) {
        unsigned t = (tid >= o) ? s[tid - o] : 0u;
        __syncthreads();
        s[tid] += t;
        __syncthreads();
    }
    if (tid < NBLK_N) bs[tid] = s[tid] - v;   // exclusive
}

__global__ __launch_bounds__(256) void k_scan_final(const unsigned* __restrict__ hist,
                                                    const unsigned* __restrict__ bs,
                                                    unsigned* __restrict__ rowptr,
                                                    unsigned* __restrict__ cursor) {
    __shared__ unsigned s[256];
    int tid = threadIdx.x;
    int i = blockIdx.x * 256 + tid;
    unsigned v = (i < N_NODES) ? hist[i] : 0u;
    s[tid] = v;
    __syncthreads();
    for (int o = 1; o < 256; o <<= 1) {
        unsigned t = (tid >= o) ? s[tid - o] : 0u;
        __syncthreads();
        s[tid] += t;
        __syncthreads();
    }
    unsigned excl = s[tid] - v + bs[blockIdx.x];
    if (i < N_NODES) {
        rowptr[i] = excl;
        cursor[i] = excl;
        if (i == N_NODES - 1) rowptr[N_NODES] = excl + v;  // == E
    }
}

__global__ __launch_bounds__(256) void k_fill(const int* __restrict__ src,
                                              const int* __restrict__ dst,
                                              unsigned* __restrict__ cursor,
                                              int* __restrict__ sorted_src) {
    int e = blockIdx.x * 256 + threadIdx.x;
    if (e < N_EDGES) {
        int d = dst[e];
        unsigned pos = atomicAdd(&cursor[d], 1u);
        sorted_src[pos] = src[e];
    }
}

// ---------------- dense layers ----------------

// C[N x OUT] = A[N x K] @ W[K x OUT]; 32 rows per 256-thread block
template<int K, int OUT>
__global__ __launch_bounds__(256) void k_gemm(const float* __restrict__ A,
                                              const float* __restrict__ W,
                                              float* __restrict__ C) {
    constexpr int BR = 32;
    __shared__ float Wld[K * OUT];
    __shared__ float Ald[BR * K];
    const int tid = threadIdx.x;
    for (int i = tid; i < K * OUT; i += 256) Wld[i] = W[i];
    const long row0 = (long)blockIdx.x * BR;
    const float4* A4 = reinterpret_cast<const float4*>(A + row0 * K);
    float4* Ald4 = reinterpret_cast<float4*>(Ald);
    constexpr int NV = BR * K / 4;
    for (int i = tid; i < NV; i += 256) Ald4[i] = A4[i];
    __syncthreads();

    constexpr int RG = 256 / OUT;
    constexpr int RPT = BR / RG;
    const int col = tid % OUT;
    const int rg = tid / OUT;
    float acc[RPT];
#pragma unroll
    for (int j = 0; j < RPT; ++j) acc[j] = 0.f;
    for (int k = 0; k < K; ++k) {
        float w = Wld[k * OUT + col];
#pragma unroll
        for (int j = 0; j < RPT; ++j)
            acc[j] += Ald[(rg + j * RG) * K + k] * w;
    }
#pragma unroll
    for (int j = 0; j < RPT; ++j)
        C[(row0 + rg + j * RG) * OUT + col] = acc[j];
}

// one node per 64-lane wave; gather in-edges from CSR; fused self-loop+bias+tanh
__global__ __launch_bounds__(256) void k_agg(const float* __restrict__ xl,
                                             const float* __restrict__ dinv,
                                             const unsigned* __restrict__ rowptr,
                                             const int* __restrict__ ssrc,
                                             const float* __restrict__ bias,
                                             float* __restrict__ h) {
    const int node = blockIdx.x * 4 + (threadIdx.x >> 6);
    const int lane = threadIdx.x & 63;
    const float di = dinv[node];
    float acc = xl[(size_t)node * 64 + lane] * (di * di) + bias[lane];
    const unsigned beg = rowptr[node], end = rowptr[node + 1];
    for (unsigned j = beg; j < end; ++j) {
        int s = ssrc[j];
        acc += xl[(size_t)s * 64 + lane] * (dinv[s] * di);
    }
    h[(size_t)node * 64 + lane] = tanhf(acc);
}

// fused FC stack: tanh(h@W0+b0) -> tanh(@W1+b1) -> @W2+b2 ; 32 rows/block
__global__ __launch_bounds__(256) void k_fc(const float* __restrict__ h2,
                                            const float* __restrict__ fW0, const float* __restrict__ fb0,
                                            const float* __restrict__ fW1, const float* __restrict__ fb1,
                                            const float* __restrict__ fW2, const float* __restrict__ fb2,
                                            float* __restrict__ out) {
    constexpr int BR = 32;
    __shared__ float W0[64 * 64];
    __shared__ float W1[64 * 32];
    __shared__ float Hin[BR * 64];
    __shared__ float Ht[BR * 64];
    const int tid = threadIdx.x;
    for (int i = tid; i < 64 * 64; i += 256) W0[i] = fW0[i];
    for (int i = tid; i < 64 * 32; i += 256) W1[i] = fW1[i];
    const long row0 = (long)blockIdx.x * BR;
    const float4* H4 = reinterpret_cast<const float4*>(h2 + row0 * 64);
    float4* Hin4 = reinterpret_cast<float4*>(Hin);
    for (int i = tid; i < BR * 16; i += 256) Hin4[i] = H4[i];
    __syncthreads();

    // fc0: 64 cols, 4 row-groups, 8 rows each
    {
        const int col = tid & 63, rg = tid >> 6;
#pragma unroll
        for (int j = 0; j < 8; ++j) {
            const int r = rg + j * 4;
            float a = fb0[col];
            for (int k = 0; k < 64; ++k) a += Hin[r * 64 + k] * W0[k * 64 + col];
            Ht[r * 64 + col] = tanhf(a);
        }
    }
    __syncthreads();
    // fc1: 32 cols, 8 row-groups, 4 rows each; write into Hin (stride 32)
    {
        const int col = tid & 31, rg = tid >> 5;
#pragma unroll
        for (int j = 0; j < 4; ++j) {
            const int r = rg + j * 8;
            float a = fb1[col];
            for (int k = 0; k < 64; ++k) a += Ht[r * 64 + k] * W1[k * 32 + col];
            Hin[r * 32 + col] = tanhf(a);
        }
    }
    __syncthreads();
    // fc2: 32 -> 1; threads 0..31 each produce one row
    if (tid < BR) {
        float a = fb2[0];
        for (int k = 0; k < 32; ++k) a += Hin[tid * 32 + k] * fW2[k];
        out[row0 + tid] = a;
    }
}

// ---------------- launch ----------------

extern "C" void kernel_launch(void* const* d_in, const int* in_sizes, int n_in,
                              void* d_out, int out_size, void* d_ws, size_t ws_size,
                              hipStream_t stream) {
    const float* x    = (const float*)d_in[0];
    const int*   eidx = (const int*)d_in[1];
    const float* cW0  = (const float*)d_in[2];
    const float* cb0  = (const float*)d_in[3];
    const float* cW1  = (const float*)d_in[4];
    const float* cb1  = (const float*)d_in[5];
    const float* fW0  = (const float*)d_in[6];
    const float* fb0  = (const float*)d_in[7];
    const float* fW1  = (const float*)d_in[8];
    const float* fb1  = (const float*)d_in[9];
    const float* fW2  = (const float*)d_in[10];
    const float* fb2  = (const float*)d_in[11];
    float* out = (float*)d_out;

    const int* src = eidx;
    const int* dst = eidx + N_EDGES;

    char* ws = (char*)d_ws;
    unsigned* hist   = (unsigned*)(ws);                 // 400,000 B (also block sums live past end? no)
    unsigned* rowptr = (unsigned*)(ws + 400000);        // 400,004 B
    float*    dinv   = (float*)   (ws + 800016);        // 400,000 B
    unsigned* cursor = (unsigned*)(ws + 1200016);       // 400,000 B
    unsigned* bs     = (unsigned*)(ws + 1600016);       // 391*4 = 1,564 B
    int*      ssrc   = (int*)     (ws + 1601584);       // 6,400,000 B
    float*    bufA   = (float*)   (ws + 8001584);       // 25,600,000 B
    float*    bufB   = (float*)   (ws + 33601584);      // 25,600,000 B -> ends 59,201,584

    const int gE   = (N_EDGES + 255) / 256;   // 6250
    const int gRow = N_NODES / 32;            // 3125
    const int gAgg = N_NODES / 4;             // 25000

    // CSR build + degree normalization
    k_zero_u32<<<NBLK_N, 256, 0, stream>>>(hist, N_NODES);
    k_hist<<<gE, 256, 0, stream>>>(dst, hist);
    k_dinv<<<NBLK_N, 256, 0, stream>>>(hist, dinv);
    k_blocksum<<<NBLK_N, 256, 0, stream>>>(hist, bs);
    k_scanbs<<<1, 512, 0, stream>>>(bs);
    k_scan_final<<<NBLK_N, 256, 0, stream>>>(hist, bs, rowptr, cursor);
    k_fill<<<gE, 256, 0, stream>>>(src, dst, cursor, ssrc);

    // conv0
    k_gemm<128, 64><<<gRow, 256, 0, stream>>>(x, cW0, bufA);
    k_agg<<<gAgg, 256, 0, stream>>>(bufA, dinv, rowptr, ssrc, cb0, bufB);
    // conv1
    k_gemm<64, 64><<<gRow, 256, 0, stream>>>(bufB, cW1, bufA);
    k_agg<<<gAgg, 256, 0, stream>>>(bufA, dinv, rowptr, ssrc, cb1, bufB);
    // fc stack
    k_fc<<<gRow, 256, 0, stream>>>(bufB, fW0, fb0, fW1, fb1, fW2, fb2, out);
}

// Round 3
// 508.971 us; speedup vs baseline: 1.9060x; 1.3003x over previous
//
#include <hip/hip_runtime.h>
#include <math.h>

#define N_NODES 100000
#define N_EDGES 1600000
#define NBLK_N 391   // ceil(N/256)

// ---------------- CSR build ----------------

__global__ __launch_bounds__(256) void k_zero_u32(unsigned* __restrict__ p, int n) {
    int i = blockIdx.x * 256 + threadIdx.x;
    if (i < n) p[i] = 0u;
}

__global__ __launch_bounds__(256) void k_hist(const int* __restrict__ dst,
                                              unsigned* __restrict__ hist) {
    int e = blockIdx.x * 256 + threadIdx.x;
    if (e < N_EDGES) atomicAdd(&hist[dst[e]], 1u);
}

__global__ __launch_bounds__(256) void k_blocksum(const unsigned* __restrict__ hist,
                                                  unsigned* __restrict__ bs) {
    __shared__ unsigned s[256];
    int i = blockIdx.x * 256 + threadIdx.x;
    unsigned v = (i < N_NODES) ? hist[i] : 0u;
    s[threadIdx.x] = v;
    __syncthreads();
    for (int o = 128; o > 0; o >>= 1) {
        if (threadIdx.x < o) s[threadIdx.x] += s[threadIdx.x + o];
        __syncthreads();
    }
    if (threadIdx.x == 0) bs[blockIdx.x] = s[0];
}

// single block: exclusive scan of bs[NBLK_N] (NBLK_N <= 512)
__global__ __launch_bounds__(512) void k_scanbs(unsigned* __restrict__ bs) {
    __shared__ unsigned s[512];
    int tid = threadIdx.x;
    unsigned v = (tid < NBLK_N) ? bs[tid] : 0u;
    s[tid] = v;
    __syncthreads();
    for (int o = 1; o < 512; o <<= 1) {
        unsigned t = (tid >= o) ? s[tid - o] : 0u;
        __syncthreads();
        s[tid] += t;
        __syncthreads();
    }
    if (tid < NBLK_N) bs[tid] = s[tid] - v;   // exclusive
}

// also computes dinv = rsqrt(deg+1)
__global__ __launch_bounds__(256) void k_scan_final(const unsigned* __restrict__ hist,
                                                    const unsigned* __restrict__ bs,
                                                    unsigned* __restrict__ rowptr,
                                                    unsigned* __restrict__ cursor,
                                                    float* __restrict__ dinv) {
    __shared__ unsigned s[256];
    int tid = threadIdx.x;
    int i = blockIdx.x * 256 + tid;
    unsigned v = (i < N_NODES) ? hist[i] : 0u;
    s[tid] = v;
    __syncthreads();
    for (int o = 1; o < 256; o <<= 1) {
        unsigned t = (tid >= o) ? s[tid - o] : 0u;
        __syncthreads();
        s[tid] += t;
        __syncthreads();
    }
    unsigned excl = s[tid] - v + bs[blockIdx.x];
    if (i < N_NODES) {
        rowptr[i] = excl;
        cursor[i] = excl;
        dinv[i] = rsqrtf((float)(v + 1u));
        if (i == N_NODES - 1) rowptr[N_NODES] = excl + v;  // == E
    }
}

__global__ __launch_bounds__(256) void k_fill(const int* __restrict__ src,
                                              const int* __restrict__ dst,
                                              unsigned* __restrict__ cursor,
                                              int* __restrict__ sorted_src) {
    int e = blockIdx.x * 256 + threadIdx.x;
    if (e < N_EDGES) {
        int d = dst[e];
        unsigned pos = atomicAdd(&cursor[d], 1u);
        sorted_src[pos] = src[e];
    }
}

// ---------------- dense layers ----------------

// C[N x OUT] = (A[N x K] @ W[K x OUT]) * (SCALE ? dinv[row] : 1)
// 256 threads, 32 rows per block; float4 LDS reads over k.
template<int K, int OUT, bool SCALE>
__global__ __launch_bounds__(256) void k_gemm(const float* __restrict__ A,
                                              const float* __restrict__ W,
                                              const float* __restrict__ dinv,
                                              float* __restrict__ C) {
    constexpr int BR = 32;
    __shared__ float Wld[K * OUT];
    __shared__ float Ald[BR * K];
    const int tid = threadIdx.x;
    for (int i = tid; i < K * OUT; i += 256) Wld[i] = W[i];
    const long row0 = (long)blockIdx.x * BR;
    const float4* A4 = reinterpret_cast<const float4*>(A + row0 * K);
    float4* Ald4w = reinterpret_cast<float4*>(Ald);
    constexpr int NV = BR * K / 4;
    for (int i = tid; i < NV; i += 256) Ald4w[i] = A4[i];
    __syncthreads();

    constexpr int RG = 256 / OUT;   // row groups
    constexpr int RPT = BR / RG;    // rows per thread
    const int col = tid % OUT;
    const int rg = tid / OUT;
    const float4* Ald4 = reinterpret_cast<const float4*>(Ald);
    float acc[RPT];
#pragma unroll
    for (int j = 0; j < RPT; ++j) acc[j] = 0.f;
    for (int k4 = 0; k4 < K; k4 += 4) {
        const float w0 = Wld[(k4 + 0) * OUT + col];
        const float w1 = Wld[(k4 + 1) * OUT + col];
        const float w2 = Wld[(k4 + 2) * OUT + col];
        const float w3 = Wld[(k4 + 3) * OUT + col];
#pragma unroll
        for (int j = 0; j < RPT; ++j) {
            const float4 a = Ald4[((rg + j * RG) * K + k4) >> 2];
            acc[j] = fmaf(a.x, w0, fmaf(a.y, w1, fmaf(a.z, w2, fmaf(a.w, w3, acc[j]))));
        }
    }
#pragma unroll
    for (int j = 0; j < RPT; ++j) {
        const long r = row0 + rg + j * RG;
        float v = acc[j];
        if (SCALE) v *= dinv[r];
        C[r * OUT + col] = v;
    }
}

// one node per 64-lane wave; xl is pre-scaled by dinv[row].
// lane = 16*g + l : group g handles edges j≡g (mod 4), lane covers features l*4..l*4+3.
// h[node] = tanh(dinv[node]*(sum_{s in in(node)} xl[s] + xl[node]) + bias)
__global__ __launch_bounds__(256) void k_agg(const float* __restrict__ xl,
                                             const float* __restrict__ dinv,
                                             const unsigned* __restrict__ rowptr,
                                             const int* __restrict__ ssrc,
                                             const float* __restrict__ bias,
                                             float* __restrict__ h) {
    const int node = blockIdx.x * 4 + (threadIdx.x >> 6);
    const int lane = threadIdx.x & 63;
    const int g = lane >> 4;
    const int l = lane & 15;
    const float4* xl4 = reinterpret_cast<const float4*>(xl);

    const unsigned beg = rowptr[node], end = rowptr[node + 1];
    float4 a0 = {0.f, 0.f, 0.f, 0.f};
    float4 a1 = {0.f, 0.f, 0.f, 0.f};
    if (g == 0) a0 = xl4[(size_t)node * 16 + l];   // self-loop term

    unsigned j = beg + g;
    for (; j + 4 < end; j += 8) {
        const int s0 = ssrc[j];
        const int s1 = ssrc[j + 4];
        const float4 v0 = xl4[(size_t)s0 * 16 + l];
        const float4 v1 = xl4[(size_t)s1 * 16 + l];
        a0.x += v0.x; a0.y += v0.y; a0.z += v0.z; a0.w += v0.w;
        a1.x += v1.x; a1.y += v1.y; a1.z += v1.z; a1.w += v1.w;
    }
    if (j < end) {
        const int s = ssrc[j];
        const float4 v = xl4[(size_t)s * 16 + l];
        a0.x += v.x; a0.y += v.y; a0.z += v.z; a0.w += v.w;
    }
    a0.x += a1.x; a0.y += a1.y; a0.z += a1.z; a0.w += a1.w;

    // reduce across the 4 lane-groups
    a0.x += __shfl_xor(a0.x, 16); a0.y += __shfl_xor(a0.y, 16);
    a0.z += __shfl_xor(a0.z, 16); a0.w += __shfl_xor(a0.w, 16);
    a0.x += __shfl_xor(a0.x, 32); a0.y += __shfl_xor(a0.y, 32);
    a0.z += __shfl_xor(a0.z, 32); a0.w += __shfl_xor(a0.w, 32);

    if (g == 0) {
        const float di = dinv[node];
        const float4 b = reinterpret_cast<const float4*>(bias)[l];
        float4 r;
        r.x = tanhf(fmaf(a0.x, di, b.x));
        r.y = tanhf(fmaf(a0.y, di, b.y));
        r.z = tanhf(fmaf(a0.z, di, b.z));
        r.w = tanhf(fmaf(a0.w, di, b.w));
        reinterpret_cast<float4*>(h)[(size_t)node * 16 + l] = r;
    }
}

// fused FC stack: tanh(h@W0+b0) -> tanh(@W1+b1) -> @W2+b2 ; 32 rows/block
__global__ __launch_bounds__(256) void k_fc(const float* __restrict__ h2,
                                            const float* __restrict__ fW0, const float* __restrict__ fb0,
                                            const float* __restrict__ fW1, const float* __restrict__ fb1,
                                            const float* __restrict__ fW2, const float* __restrict__ fb2,
                                            float* __restrict__ out) {
    constexpr int BR = 32;
    __shared__ float W0[64 * 64];
    __shared__ float W1[64 * 32];
    __shared__ float Hin[BR * 64];
    __shared__ float Ht[BR * 64];
    const int tid = threadIdx.x;
    for (int i = tid; i < 64 * 64; i += 256) W0[i] = fW0[i];
    for (int i = tid; i < 64 * 32; i += 256) W1[i] = fW1[i];
    const long row0 = (long)blockIdx.x * BR;
    const float4* H4 = reinterpret_cast<const float4*>(h2 + row0 * 64);
    float4* Hin4 = reinterpret_cast<float4*>(Hin);
    for (int i = tid; i < BR * 16; i += 256) Hin4[i] = H4[i];
    __syncthreads();

    {
        const int col = tid & 63, rg = tid >> 6;
#pragma unroll
        for (int j = 0; j < 8; ++j) {
            const int r = rg + j * 4;
            float a = fb0[col];
            for (int k = 0; k < 64; ++k) a += Hin[r * 64 + k] * W0[k * 64 + col];
            Ht[r * 64 + col] = tanhf(a);
        }
    }
    __syncthreads();
    {
        const int col = tid & 31, rg = tid >> 5;
#pragma unroll
        for (int j = 0; j < 4; ++j) {
            const int r = rg + j * 8;
            float a = fb1[col];
            for (int k = 0; k < 64; ++k) a += Ht[r * 64 + k] * W1[k * 32 + col];
            Hin[r * 32 + col] = tanhf(a);
        }
    }
    __syncthreads();
    if (tid < BR) {
        float a = fb2[0];
        for (int k = 0; k < 32; ++k) a += Hin[tid * 32 + k] * fW2[k];
        out[row0 + tid] = a;
    }
}

// ---------------- launch ----------------

extern "C" void kernel_launch(void* const* d_in, const int* in_sizes, int n_in,
                              void* d_out, int out_size, void* d_ws, size_t ws_size,
                              hipStream_t stream) {
    const float* x    = (const float*)d_in[0];
    const int*   eidx = (const int*)d_in[1];
    const float* cW0  = (const float*)d_in[2];
    const float* cb0  = (const float*)d_in[3];
    const float* cW1  = (const float*)d_in[4];
    const float* cb1  = (const float*)d_in[5];
    const float* fW0  = (const float*)d_in[6];
    const float* fb0  = (const float*)d_in[7];
    const float* fW1  = (const float*)d_in[8];
    const float* fb1  = (const float*)d_in[9];
    const float* fW2  = (const float*)d_in[10];
    const float* fb2  = (const float*)d_in[11];
    float* out = (float*)d_out;

    const int* src = eidx;
    const int* dst = eidx + N_EDGES;

    char* ws = (char*)d_ws;
    unsigned* hist   = (unsigned*)(ws);
    unsigned* rowptr = (unsigned*)(ws + 400000);
    float*    dinv   = (float*)   (ws + 800016);
    unsigned* cursor = (unsigned*)(ws + 1200016);
    unsigned* bs     = (unsigned*)(ws + 1600016);
    int*      ssrc   = (int*)     (ws + 1601584);
    float*    bufA   = (float*)   (ws + 8001584);
    float*    bufB   = (float*)   (ws + 33601584);

    const int gE   = (N_EDGES + 255) / 256;   // 6250
    const int gRow = N_NODES / 32;            // 3125
    const int gAgg = N_NODES / 4;             // 25000

    // CSR build + degree normalization
    k_zero_u32<<<NBLK_N, 256, 0, stream>>>(hist, N_NODES);
    k_hist<<<gE, 256, 0, stream>>>(dst, hist);
    k_blocksum<<<NBLK_N, 256, 0, stream>>>(hist, bs);
    k_scanbs<<<1, 512, 0, stream>>>(bs);
    k_scan_final<<<NBLK_N, 256, 0, stream>>>(hist, bs, rowptr, cursor, dinv);
    k_fill<<<gE, 256, 0, stream>>>(src, dst, cursor, ssrc);

    // conv0: bufA = (x @ cW0) * dinv[row]
    k_gemm<128, 64, true><<<gRow, 256, 0, stream>>>(x, cW0, dinv, bufA);
    k_agg<<<gAgg, 256, 0, stream>>>(bufA, dinv, rowptr, ssrc, cb0, bufB);
    // conv1: bufA = (h1 @ cW1) * dinv[row]
    k_gemm<64, 64, true><<<gRow, 256, 0, stream>>>(bufB, cW1, dinv, bufA);
    k_agg<<<gAgg, 256, 0, stream>>>(bufA, dinv, rowptr, ssrc, cb1, bufB);
    // fc stack
    k_fc<<<gRow, 256, 0, stream>>>(bufB, fW0, fb0, fW1, fb1, fW2, fb2, out);
}

// Round 4
// 367.676 us; speedup vs baseline: 2.6384x; 1.3843x over previous
//
#include <hip/hip_runtime.h>
#include <math.h>

#define N_NODES 100000
#define N_EDGES 1600000
#define NBLK_N 391   // ceil(N/256)
#define NB     391   // buckets of 256 nodes
#define CHUNK  4096  // edges per k_bin block
#define NBLK_A 391   // ceil(E/CHUNK)

typedef unsigned short ushort_t;

__device__ inline unsigned short f2bf(float f) {
    unsigned u = __float_as_uint(f);
    unsigned r = (u + 0x7FFFu + ((u >> 16) & 1u)) >> 16;
    return (unsigned short)r;
}
__device__ inline void acc_bf4(float4& a, ushort4 v) {
    a.x += __uint_as_float(((unsigned)v.x) << 16);
    a.y += __uint_as_float(((unsigned)v.y) << 16);
    a.z += __uint_as_float(((unsigned)v.z) << 16);
    a.w += __uint_as_float(((unsigned)v.w) << 16);
}

// ---------------- degree + rowptr ----------------

__global__ __launch_bounds__(256) void k_zero_u32(unsigned* __restrict__ p, int n) {
    int i = blockIdx.x * 256 + threadIdx.x;
    if (i < n) p[i] = 0u;
}

__global__ __launch_bounds__(256) void k_hist(const int* __restrict__ dst,
                                              unsigned* __restrict__ hist) {
    int e = blockIdx.x * 256 + threadIdx.x;
    if (e < N_EDGES) atomicAdd(&hist[dst[e]], 1u);
}

__global__ __launch_bounds__(256) void k_blocksum(const unsigned* __restrict__ hist,
                                                  unsigned* __restrict__ bs) {
    __shared__ unsigned s[256];
    int i = blockIdx.x * 256 + threadIdx.x;
    unsigned v = (i < N_NODES) ? hist[i] : 0u;
    s[threadIdx.x] = v;
    __syncthreads();
    for (int o = 128; o > 0; o >>= 1) {
        if (threadIdx.x < o) s[threadIdx.x] += s[threadIdx.x + o];
        __syncthreads();
    }
    if (threadIdx.x == 0) bs[blockIdx.x] = s[0];
}

__global__ __launch_bounds__(512) void k_scanbs(unsigned* __restrict__ bs) {
    __shared__ unsigned s[512];
    int tid = threadIdx.x;
    unsigned v = (tid < NBLK_N) ? bs[tid] : 0u;
    s[tid] = v;
    __syncthreads();
    for (int o = 1; o < 512; o <<= 1) {
        unsigned t = (tid >= o) ? s[tid - o] : 0u;
        __syncthreads();
        s[tid] += t;
        __syncthreads();
    }
    if (tid < NBLK_N) bs[tid] = s[tid] - v;   // exclusive
}

__global__ __launch_bounds__(256) void k_scan_final(const unsigned* __restrict__ hist,
                                                    const unsigned* __restrict__ bs,
                                                    unsigned* __restrict__ rowptr,
                                                    float* __restrict__ dinv) {
    __shared__ unsigned s[256];
    int tid = threadIdx.x;
    int i = blockIdx.x * 256 + tid;
    unsigned v = (i < N_NODES) ? hist[i] : 0u;
    s[tid] = v;
    __syncthreads();
    for (int o = 1; o < 256; o <<= 1) {
        unsigned t = (tid >= o) ? s[tid - o] : 0u;
        __syncthreads();
        s[tid] += t;
        __syncthreads();
    }
    unsigned excl = s[tid] - v + bs[blockIdx.x];
    if (i < N_NODES) {
        rowptr[i] = excl;
        dinv[i] = rsqrtf((float)(v + 1u));
        if (i == N_NODES - 1) rowptr[N_NODES] = excl + v;  // == E
    }
}

__global__ __launch_bounds__(256) void k_init_bcur(const unsigned* __restrict__ rowptr,
                                                   unsigned* __restrict__ gbcur) {
    int t = blockIdx.x * 256 + threadIdx.x;
    if (t < NB) gbcur[t] = rowptr[t * 256];
}

// ---------------- phase A: LDS multisplit into 391 buckets ----------------
// binned[pos] = (src<<8) | (dst&255), grouped by bucket = dst>>8
__global__ __launch_bounds__(256) void k_bin(const int* __restrict__ src,
                                             const int* __restrict__ dst,
                                             unsigned* __restrict__ gbcur,
                                             unsigned* __restrict__ binned) {
    __shared__ unsigned cntA[NB];
    __shared__ unsigned excl[NB];
    __shared__ unsigned gbase[NB];
    __shared__ unsigned scanbuf[512];
    __shared__ unsigned data[CHUNK];
    const int tid = threadIdx.x;
    const long e0 = (long)blockIdx.x * CHUNK;

    for (int i = tid; i < NB; i += 256) cntA[i] = 0u;
    __syncthreads();
    for (int i = tid; i < CHUNK; i += 256) {
        long e = e0 + i;
        if (e < N_EDGES) atomicAdd(&cntA[((unsigned)dst[e]) >> 8], 1u);
    }
    __syncthreads();
    scanbuf[tid] = (tid < NB) ? cntA[tid] : 0u;
    scanbuf[tid + 256] = (tid + 256 < NB) ? cntA[tid + 256] : 0u;
    __syncthreads();
    for (int o = 1; o < 512; o <<= 1) {
        unsigned v0 = (tid >= o) ? scanbuf[tid - o] : 0u;
        unsigned v1 = (tid + 256 >= o) ? scanbuf[tid + 256 - o] : 0u;
        __syncthreads();
        scanbuf[tid] += v0;
        scanbuf[tid + 256] += v1;
        __syncthreads();
    }
    for (int b = tid; b < NB; b += 256) {
        unsigned c = cntA[b];
        excl[b] = scanbuf[b] - c;
        gbase[b] = c ? atomicAdd(&gbcur[b], c) : 0u;
    }
    __syncthreads();
    for (int i = tid; i < NB; i += 256) cntA[i] = 0u;
    __syncthreads();
    for (int i = tid; i < CHUNK; i += 256) {
        long e = e0 + i;
        if (e < N_EDGES) {
            unsigned d = (unsigned)dst[e];
            unsigned b = d >> 8;
            unsigned slot = excl[b] + atomicAdd(&cntA[b], 1u);
            data[slot] = (((unsigned)src[e]) << 8) | (d & 255u);
        }
    }
    __syncthreads();
    const int w = tid >> 6, lane = tid & 63;
    for (int b = w; b < NB; b += 4) {
        unsigned c = cntA[b];
        unsigned sb = excl[b], gb = gbase[b];
        for (unsigned k = lane; k < c; k += 64)
            binned[gb + k] = data[sb + k];
    }
}

// ---------------- phase B: per-bucket CSR fill (LDS cursors) ----------------
__global__ __launch_bounds__(256) void k_csr_fill(const unsigned* __restrict__ binned,
                                                  const unsigned* __restrict__ rowptr,
                                                  int* __restrict__ ssrc) {
    __shared__ unsigned cur[256];
    const int b = blockIdx.x;
    const int tid = threadIdx.x;
    const int n0 = b * 256;
    const int n1 = (n0 + 256 < N_NODES) ? n0 + 256 : N_NODES;
    if (tid < n1 - n0) cur[tid] = rowptr[n0 + tid];
    __syncthreads();
    const unsigned beg = rowptr[n0], end = rowptr[n1];
    for (unsigned i = beg + tid; i < end; i += 256) {
        unsigned p = binned[i];
        unsigned pos = atomicAdd(&cur[p & 255u], 1u);
        ssrc[pos] = (int)(p >> 8);
    }
}

// ---------------- dense layers ----------------

// xlb[N x OUT] (bf16) = (A[N x K] @ W[K x OUT]) * dinv[row]
template<int K, int OUT>
__global__ __launch_bounds__(256) void k_gemm_bf(const float* __restrict__ A,
                                                 const float* __restrict__ W,
                                                 const float* __restrict__ dinv,
                                                 ushort_t* __restrict__ C) {
    constexpr int BR = 32;
    __shared__ float Wld[K * OUT];
    __shared__ float Ald[BR * K];
    const int tid = threadIdx.x;
    for (int i = tid; i < K * OUT; i += 256) Wld[i] = W[i];
    const long row0 = (long)blockIdx.x * BR;
    const float4* A4 = reinterpret_cast<const float4*>(A + row0 * K);
    float4* Ald4w = reinterpret_cast<float4*>(Ald);
    constexpr int NV = BR * K / 4;
    for (int i = tid; i < NV; i += 256) Ald4w[i] = A4[i];
    __syncthreads();

    constexpr int RG = 256 / OUT;
    constexpr int RPT = BR / RG;
    const int col = tid % OUT;
    const int rg = tid / OUT;
    const float4* Ald4 = reinterpret_cast<const float4*>(Ald);
    float acc[RPT];
#pragma unroll
    for (int j = 0; j < RPT; ++j) acc[j] = 0.f;
    for (int k4 = 0; k4 < K; k4 += 4) {
        const float w0 = Wld[(k4 + 0) * OUT + col];
        const float w1 = Wld[(k4 + 1) * OUT + col];
        const float w2 = Wld[(k4 + 2) * OUT + col];
        const float w3 = Wld[(k4 + 3) * OUT + col];
#pragma unroll
        for (int j = 0; j < RPT; ++j) {
            const float4 a = Ald4[((rg + j * RG) * K + k4) >> 2];
            acc[j] = fmaf(a.x, w0, fmaf(a.y, w1, fmaf(a.z, w2, fmaf(a.w, w3, acc[j]))));
        }
    }
#pragma unroll
    for (int j = 0; j < RPT; ++j) {
        const long r = row0 + rg + j * RG;
        C[r * OUT + col] = f2bf(acc[j] * dinv[r]);
    }
}

// one node per 64-lane wave; xlb bf16, pre-scaled by dinv[row]; fp32 accumulate.
__global__ __launch_bounds__(256) void k_agg(const ushort_t* __restrict__ xlb,
                                             const float* __restrict__ dinv,
                                             const unsigned* __restrict__ rowptr,
                                             const int* __restrict__ ssrc,
                                             const float* __restrict__ bias,
                                             float* __restrict__ h) {
    const int node = blockIdx.x * 4 + (threadIdx.x >> 6);
    const int lane = threadIdx.x & 63;
    const int g = lane >> 4;
    const int l = lane & 15;
    const ushort4* xb4 = reinterpret_cast<const ushort4*>(xlb);

    const unsigned beg = rowptr[node], end = rowptr[node + 1];
    float4 a0 = {0.f, 0.f, 0.f, 0.f};
    float4 a1 = {0.f, 0.f, 0.f, 0.f};
    if (g == 0) acc_bf4(a0, xb4[(size_t)node * 16 + l]);   // self-loop

    unsigned j = beg + g;
    for (; j + 4 < end; j += 8) {
        const int s0 = ssrc[j];
        const int s1 = ssrc[j + 4];
        const ushort4 v0 = xb4[(size_t)s0 * 16 + l];
        const ushort4 v1 = xb4[(size_t)s1 * 16 + l];
        acc_bf4(a0, v0);
        acc_bf4(a1, v1);
    }
    if (j < end) acc_bf4(a0, xb4[(size_t)ssrc[j] * 16 + l]);
    a0.x += a1.x; a0.y += a1.y; a0.z += a1.z; a0.w += a1.w;

    a0.x += __shfl_xor(a0.x, 16); a0.y += __shfl_xor(a0.y, 16);
    a0.z += __shfl_xor(a0.z, 16); a0.w += __shfl_xor(a0.w, 16);
    a0.x += __shfl_xor(a0.x, 32); a0.y += __shfl_xor(a0.y, 32);
    a0.z += __shfl_xor(a0.z, 32); a0.w += __shfl_xor(a0.w, 32);

    if (g == 0) {
        const float di = dinv[node];
        const float4 b = reinterpret_cast<const float4*>(bias)[l];
        float4 r;
        r.x = tanhf(fmaf(a0.x, di, b.x));
        r.y = tanhf(fmaf(a0.y, di, b.y));
        r.z = tanhf(fmaf(a0.z, di, b.z));
        r.w = tanhf(fmaf(a0.w, di, b.w));
        reinterpret_cast<float4*>(h)[(size_t)node * 16 + l] = r;
    }
}

// fused FC stack: tanh(h@W0+b0) -> tanh(@W1+b1) -> @W2+b2 ; 32 rows/block
__global__ __launch_bounds__(256) void k_fc(const float* __restrict__ h2,
                                            const float* __restrict__ fW0, const float* __restrict__ fb0,
                                            const float* __restrict__ fW1, const float* __restrict__ fb1,
                                            const float* __restrict__ fW2, const float* __restrict__ fb2,
                                            float* __restrict__ out) {
    constexpr int BR = 32;
    __shared__ float W0[64 * 64];
    __shared__ float W1[64 * 32];
    __shared__ float Hin[BR * 64];
    __shared__ float Ht[BR * 64];
    const int tid = threadIdx.x;
    for (int i = tid; i < 64 * 64; i += 256) W0[i] = fW0[i];
    for (int i = tid; i < 64 * 32; i += 256) W1[i] = fW1[i];
    const long row0 = (long)blockIdx.x * BR;
    const float4* H4 = reinterpret_cast<const float4*>(h2 + row0 * 64);
    float4* Hin4 = reinterpret_cast<float4*>(Hin);
    for (int i = tid; i < BR * 16; i += 256) Hin4[i] = H4[i];
    __syncthreads();

    {
        const int col = tid & 63, rg = tid >> 6;
#pragma unroll
        for (int j = 0; j < 8; ++j) {
            const int r = rg + j * 4;
            float a = fb0[col];
            for (int k = 0; k < 64; ++k) a += Hin[r * 64 + k] * W0[k * 64 + col];
            Ht[r * 64 + col] = tanhf(a);
        }
    }
    __syncthreads();
    {
        const int col = tid & 31, rg = tid >> 5;
#pragma unroll
        for (int j = 0; j < 4; ++j) {
            const int r = rg + j * 8;
            float a = fb1[col];
            for (int k = 0; k < 64; ++k) a += Ht[r * 64 + k] * W1[k * 32 + col];
            Hin[r * 32 + col] = tanhf(a);
        }
    }
    __syncthreads();
    if (tid < BR) {
        float a = fb2[0];
        for (int k = 0; k < 32; ++k) a += Hin[tid * 32 + k] * fW2[k];
        out[row0 + tid] = a;
    }
}

// ---------------- launch ----------------

extern "C" void kernel_launch(void* const* d_in, const int* in_sizes, int n_in,
                              void* d_out, int out_size, void* d_ws, size_t ws_size,
                              hipStream_t stream) {
    const float* x    = (const float*)d_in[0];
    const int*   eidx = (const int*)d_in[1];
    const float* cW0  = (const float*)d_in[2];
    const float* cb0  = (const float*)d_in[3];
    const float* cW1  = (const float*)d_in[4];
    const float* cb1  = (const float*)d_in[5];
    const float* fW0  = (const float*)d_in[6];
    const float* fb0  = (const float*)d_in[7];
    const float* fW1  = (const float*)d_in[8];
    const float* fb1  = (const float*)d_in[9];
    const float* fW2  = (const float*)d_in[10];
    const float* fb2  = (const float*)d_in[11];
    float* out = (float*)d_out;

    const int* src = eidx;
    const int* dst = eidx + N_EDGES;

    char* ws = (char*)d_ws;
    unsigned* hist   = (unsigned*)(ws);                  // 400,000
    unsigned* rowptr = (unsigned*)(ws + 400000);         // 400,004
    float*    dinv   = (float*)   (ws + 800016);         // 400,000
    unsigned* bs     = (unsigned*)(ws + 1200016);        // 1,564
    unsigned* gbcur  = (unsigned*)(ws + 1201584);        // 1,564
    int*      ssrc   = (int*)     (ws + 1203200);        // 6,400,000
    ushort_t* xlb    = (ushort_t*)(ws + 7603200);        // 12,800,000
    unsigned* binned = (unsigned*)(ws + 20403200);       // 6,400,000
    float*    bufB   = (float*)   (ws + 26803200);       // 25,600,000 -> ends 52,403,200

    const int gE   = (N_EDGES + 255) / 256;   // 6250
    const int gRow = N_NODES / 32;            // 3125
    const int gAgg = N_NODES / 4;             // 25000

    // rowptr + dinv
    k_zero_u32<<<NBLK_N, 256, 0, stream>>>(hist, N_NODES);
    k_hist<<<gE, 256, 0, stream>>>(dst, hist);
    k_blocksum<<<NBLK_N, 256, 0, stream>>>(hist, bs);
    k_scanbs<<<1, 512, 0, stream>>>(bs);
    k_scan_final<<<NBLK_N, 256, 0, stream>>>(hist, bs, rowptr, dinv);
    // CSR fill via two-phase multisplit
    k_init_bcur<<<2, 256, 0, stream>>>(rowptr, gbcur);
    k_bin<<<NBLK_A, 256, 0, stream>>>(src, dst, gbcur, binned);
    k_csr_fill<<<NB, 256, 0, stream>>>(binned, rowptr, ssrc);

    // conv0
    k_gemm_bf<128, 64><<<gRow, 256, 0, stream>>>(x, cW0, dinv, xlb);
    k_agg<<<gAgg, 256, 0, stream>>>(xlb, dinv, rowptr, ssrc, cb0, bufB);
    // conv1
    k_gemm_bf<64, 64><<<gRow, 256, 0, stream>>>(bufB, cW1, dinv, xlb);
    k_agg<<<gAgg, 256, 0, stream>>>(xlb, dinv, rowptr, ssrc, cb1, bufB);
    // fc stack
    k_fc<<<gRow, 256, 0, stream>>>(bufB, fW0, fb0, fW1, fb1, fW2, fb2, out);
}